// Round 1
// baseline (132.452 us; speedup 1.0000x reference)
//
#include <hip/hip_runtime.h>
#include <hip/hip_bf16.h>

// minGRU parallel scan, B=4 L=8192 DX=512 DH=512.
// h_t = (1-z_t) h_{t-1} + z_t g(p_t), z=sigmoid(k); linear-space chunked scan.

#define BB 4
#define LL 8192
#define DX 512
#define DH 512
#define MM (BB*LL)        // 32768 rows
#define NC 128            // chunks per batch
#define CHUNK 64          // L / NC

typedef __attribute__((ext_vector_type(8))) short bf16x8;
typedef __attribute__((ext_vector_type(4))) float f32x4;

__device__ inline unsigned f2bf(float f) {
    unsigned u = __float_as_uint(f);
    return ((u + 0x7FFFu + ((u >> 16) & 1u)) >> 16) & 0xFFFFu;
}

// f32 -> bf16 with XOR chunk-swizzle baked into the GLOBAL layout:
// element [l, d] (d = seg*64 + sub*8 + e) stored at [l, seg*64 + (sub^(l&7))*8 + e].
// A linear global_load_lds copy of a 128B row-segment then lands pre-swizzled in LDS.
__global__ void cvt_swz(const float* __restrict__ in, unsigned short* __restrict__ out, int rows) {
    int t = blockIdx.x * 256 + threadIdx.x;
    if (t >= rows * 64) return;
    int l = t >> 6, c = t & 63;
    int seg = c >> 3, sub = c & 7;
    int q = sub ^ (l & 7);
    const float* p = in + (size_t)l * 512 + c * 8;
    float4 v0 = *(const float4*)p;
    float4 v1 = *(const float4*)(p + 4);
    uint4 o;
    o.x = f2bf(v0.x) | (f2bf(v0.y) << 16);
    o.y = f2bf(v0.z) | (f2bf(v0.w) << 16);
    o.z = f2bf(v1.x) | (f2bf(v1.y) << 16);
    o.w = f2bf(v1.z) | (f2bf(v1.w) << 16);
    *(uint4*)(out + (size_t)l * 512 + seg * 64 + q * 8) = o;
}

#define GLDS(g, l) __builtin_amdgcn_global_load_lds( \
    (const __attribute__((address_space(1))) unsigned int*)(g), \
    (__attribute__((address_space(3))) unsigned int*)(l), 16, 0, 0)

// 128x128 tile, BK=64, 4 waves, dual accumulators (k and p).
// Epilogue: a = sigmoid(-k) -> aout (=d_out), b = sigmoid(k)*g(p) -> bout (ws).
__global__ __launch_bounds__(256, 2) void gemm_gate(
    const unsigned short* __restrict__ xs, const unsigned short* __restrict__ wzs,
    const unsigned short* __restrict__ whs,
    const float* __restrict__ bz, const float* __restrict__ bh,
    float* __restrict__ aout, float* __restrict__ bout)
{
    __shared__ unsigned short lx[128 * 64];
    __shared__ unsigned short lwz[128 * 64];
    __shared__ unsigned short lwh[128 * 64];
    const int tid = threadIdx.x;
    const int wid = tid >> 6, lane = tid & 63;
    const int lr = lane & 15, lg = lane >> 4;
    const int wm = wid >> 1, wn = wid & 1;
    const int m0 = blockIdx.x * 128, n0 = blockIdx.y * 128;

    f32x4 acck[4][4] = {};
    f32x4 accp[4][4] = {};

    for (int ks = 0; ks < 8; ++ks) {
#pragma unroll
        for (int j = 0; j < 4; ++j) {
            int off = wid * 1024 + j * 4096 + lane * 16;   // byte offset in 16KB tile
            int r = off >> 7, cb = off & 127;              // row, col-byte
            const char* gx = (const char*)xs  + (size_t)(m0 + r) * 1024 + ks * 128 + cb;
            const char* gz = (const char*)wzs + (size_t)(n0 + r) * 1024 + ks * 128 + cb;
            const char* gh = (const char*)whs + (size_t)(n0 + r) * 1024 + ks * 128 + cb;
            GLDS(gx, (char*)lx  + wid * 1024 + j * 4096);
            GLDS(gz, (char*)lwz + wid * 1024 + j * 4096);
            GLDS(gh, (char*)lwh + wid * 1024 + j * 4096);
        }
        __syncthreads();   // drains vmcnt -> LDS tiles complete
#pragma unroll
        for (int kk = 0; kk < 2; ++kk) {
            bf16x8 af[4], bzf[4], bhf[4];
#pragma unroll
            for (int mf = 0; mf < 4; ++mf) {
                int r = wm * 64 + mf * 16 + lr;
                int q = (kk * 4 + lg) ^ (r & 7);
                af[mf] = *(const bf16x8*)((const char*)lx + r * 128 + q * 16);
            }
#pragma unroll
            for (int nf = 0; nf < 4; ++nf) {
                int r = wn * 64 + nf * 16 + lr;
                int q = (kk * 4 + lg) ^ (r & 7);
                bzf[nf] = *(const bf16x8*)((const char*)lwz + r * 128 + q * 16);
                bhf[nf] = *(const bf16x8*)((const char*)lwh + r * 128 + q * 16);
            }
#pragma unroll
            for (int mf = 0; mf < 4; ++mf)
#pragma unroll
                for (int nf = 0; nf < 4; ++nf) {
                    acck[mf][nf] = __builtin_amdgcn_mfma_f32_16x16x32_bf16(af[mf], bzf[nf], acck[mf][nf], 0, 0, 0);
                    accp[mf][nf] = __builtin_amdgcn_mfma_f32_16x16x32_bf16(af[mf], bhf[nf], accp[mf][nf], 0, 0, 0);
                }
        }
        __syncthreads();
    }

    // epilogue: C/D layout col=lane&15, row=(lane>>4)*4+j  [m89-verified]
#pragma unroll
    for (int nf = 0; nf < 4; ++nf) {
        int h = n0 + wn * 64 + nf * 16 + lr;
        float bzv = bz[h], bhv = bh[h];
#pragma unroll
        for (int mf = 0; mf < 4; ++mf) {
#pragma unroll
            for (int j = 0; j < 4; ++j) {
                int row = m0 + wm * 64 + mf * 16 + lg * 4 + j;
                float kv = acck[mf][nf][j] + bzv;
                float pv = accp[mf][nf][j] + bhv;
                float ek = __expf(kv);
                float av = 1.0f / (1.0f + ek);           // 1 - z = sigmoid(-k)
                float zv = 1.0f - av;                    // z
                float gv = (pv >= 0.0f) ? (pv + 0.5f) : (1.0f / (1.0f + __expf(-pv)));
                size_t o = (size_t)row * 512 + h;
                aout[o] = av;
                bout[o] = zv * gv;
            }
        }
    }
}

// Phase 1: per-chunk aggregates (A = prod a, B = folded b). 2 h per thread, float2 loads.
__global__ void scan_p1(const float* __restrict__ a, const float* __restrict__ bv,
                        float* __restrict__ Aagg, float* __restrict__ Bagg) {
    int c = blockIdx.x, b = blockIdx.y;
    int h2 = threadIdx.x;
    size_t base = ((size_t)(b * LL + c * CHUNK)) * 512 + h2 * 2;
    float A0 = 1.f, A1 = 1.f, B0 = 0.f, B1 = 0.f;
    for (int t = 0; t < CHUNK; ++t) {
        float2 at = *(const float2*)(a + base);
        float2 bt = *(const float2*)(bv + base);
        B0 = fmaf(at.x, B0, bt.x);
        B1 = fmaf(at.y, B1, bt.y);
        A0 *= at.x;
        A1 *= at.y;
        base += 512;
    }
    size_t o = ((size_t)(b * NC + c)) * 512 + h2 * 2;
    *(float2*)(Aagg + o) = make_float2(A0, A1);
    *(float2*)(Bagg + o) = make_float2(B0, B1);
}

// Phase 2: sequential scan over chunk aggregates, emitting carry-in per chunk.
__global__ void scan_p2(const float* __restrict__ h0, const float* __restrict__ Aagg,
                        const float* __restrict__ Bagg, float* __restrict__ carry) {
    int g = blockIdx.x * 256 + threadIdx.x;   // 0..2047
    int b = g >> 9, h = g & 511;
    float v = h0[b * 512 + h];
    float s = (v >= 0.f) ? (v + 0.5f) : (1.f / (1.f + __expf(-v)));   // g(h_0)
    for (int c = 0; c < NC; ++c) {
        size_t o = ((size_t)(b * NC + c)) * 512 + h;
        carry[o] = s;
        s = fmaf(Aagg[o], s, Bagg[o]);
    }
}

// Phase 3: re-run recurrence within chunk with carry-in, write h. 'a' lives in d_out
// and is overwritten element-by-element after being consumed (same thread, same index).
__global__ void scan_p3(const float* __restrict__ carry, const float* __restrict__ bv,
                        float* __restrict__ out) {
    int c = blockIdx.x, b = blockIdx.y;
    int h2 = threadIdx.x;
    size_t co = ((size_t)(b * NC + c)) * 512 + h2 * 2;
    float2 s = *(const float2*)(carry + co);
    size_t base = ((size_t)(b * LL + c * CHUNK)) * 512 + h2 * 2;
    for (int t = 0; t < CHUNK; ++t) {
        float2 at = *(const float2*)(out + base);
        float2 bt = *(const float2*)(bv + base);
        s.x = fmaf(at.x, s.x, bt.x);
        s.y = fmaf(at.y, s.y, bt.y);
        *(float2*)(out + base) = s;
        base += 512;
    }
}

extern "C" void kernel_launch(void* const* d_in, const int* in_sizes, int n_in,
                              void* d_out, int out_size, void* d_ws, size_t ws_size,
                              hipStream_t stream) {
    const float* x  = (const float*)d_in[0];
    const float* h0 = (const float*)d_in[1];
    const float* Wz = (const float*)d_in[2];
    const float* bz = (const float*)d_in[3];
    const float* Wh = (const float*)d_in[4];
    const float* bh = (const float*)d_in[5];
    float* out = (float*)d_out;

    // workspace layout (total 100 MB)
    unsigned short* xs  = (unsigned short*)d_ws;                 // 32768*512 bf16 = 32 MB
    unsigned short* wzs = xs + (size_t)MM * 512;                 // 0.5 MB
    unsigned short* whs = wzs + (size_t)512 * 512;               // 0.5 MB
    float* bbuf  = (float*)(whs + (size_t)512 * 512);            // 64 MB
    float* Aagg  = bbuf + (size_t)MM * 512;                      // 1 MB
    float* Bagg  = Aagg + (size_t)BB * NC * 512;                 // 1 MB
    float* carry = Bagg + (size_t)BB * NC * 512;                 // 1 MB

    cvt_swz<<<8192, 256, 0, stream>>>(x, xs, MM);
    cvt_swz<<<128, 256, 0, stream>>>(Wz, wzs, 512);
    cvt_swz<<<128, 256, 0, stream>>>(Wh, whs, 512);
    gemm_gate<<<dim3(256, 4), 256, 0, stream>>>(xs, wzs, whs, bz, bh, out, bbuf);
    scan_p1<<<dim3(NC, BB), 256, 0, stream>>>(out, bbuf, Aagg, Bagg);
    scan_p2<<<8, 256, 0, stream>>>(h0, Aagg, Bagg, carry);
    scan_p3<<<dim3(NC, BB), 256, 0, stream>>>(carry, bbuf, out);
}

// Round 2
// 105.038 us; speedup vs baseline: 1.2610x; 1.2610x over previous
//
#include <hip/hip_runtime.h>
#include <hip/hip_bf16.h>
#include <hip/hip_fp16.h>

// minGRU parallel scan, B=4 L=8192 DX=512 DH=512.
// h_t = a_t h_{t-1} + b_t, a=sigmoid(-k), b=sigmoid(k)*g(p); linear-space chunked scan.
// R2: (a,b) packed as half2 (halves intermediate traffic); scan phase-1 fused
// into the GEMM epilogue via in-register segment compose + __shfl.

#define BB 4
#define LL 8192
#define MM (BB*LL)        // 32768 rows
#define NC 128            // chunks per batch
#define CHUNK 64          // L / NC

typedef __attribute__((ext_vector_type(8))) short bf16x8;
typedef __attribute__((ext_vector_type(4))) float f32x4;

__device__ inline unsigned f2bf(float f) {
    unsigned u = __float_as_uint(f);
    return ((u + 0x7FFFu + ((u >> 16) & 1u)) >> 16) & 0xFFFFu;
}

// f32 -> bf16 with XOR chunk-swizzle baked into the GLOBAL layout:
// element [l, d] (d = seg*64 + sub*8 + e) stored at [l, seg*64 + (sub^(l&7))*8 + e].
__global__ void cvt_swz(const float* __restrict__ in, unsigned short* __restrict__ out, int rows) {
    int t = blockIdx.x * 256 + threadIdx.x;
    if (t >= rows * 64) return;
    int l = t >> 6, c = t & 63;
    int seg = c >> 3, sub = c & 7;
    int q = sub ^ (l & 7);
    const float* p = in + (size_t)l * 512 + c * 8;
    float4 v0 = *(const float4*)p;
    float4 v1 = *(const float4*)(p + 4);
    uint4 o;
    o.x = f2bf(v0.x) | (f2bf(v0.y) << 16);
    o.y = f2bf(v0.z) | (f2bf(v0.w) << 16);
    o.z = f2bf(v1.x) | (f2bf(v1.y) << 16);
    o.w = f2bf(v1.z) | (f2bf(v1.w) << 16);
    *(uint4*)(out + (size_t)l * 512 + seg * 64 + q * 8) = o;
}

#define GLDS(g, l) __builtin_amdgcn_global_load_lds( \
    (const __attribute__((address_space(1))) unsigned int*)(g), \
    (__attribute__((address_space(3))) unsigned int*)(l), 16, 0, 0)

// 128x128 tile, BK=64, 4 waves, dual accumulators (k and p).
// Epilogue: packed half2 (a,b) -> pk buffer; fused chunk aggregates -> agg.
__global__ __launch_bounds__(256, 2) void gemm_gate(
    const unsigned short* __restrict__ xs, const unsigned short* __restrict__ wzs,
    const unsigned short* __restrict__ whs,
    const float* __restrict__ bz, const float* __restrict__ bh,
    unsigned int* __restrict__ pk, float2* __restrict__ agg)
{
    __shared__ unsigned short lx[128 * 64];
    __shared__ unsigned short lwz[128 * 64];
    __shared__ unsigned short lwh[128 * 64];
    const int tid = threadIdx.x;
    const int wid = tid >> 6, lane = tid & 63;
    const int lr = lane & 15, lg = lane >> 4;
    const int wm = wid >> 1, wn = wid & 1;
    const int m0 = blockIdx.x * 128, n0 = blockIdx.y * 128;

    f32x4 acck[4][4] = {};
    f32x4 accp[4][4] = {};

    for (int ks = 0; ks < 8; ++ks) {
#pragma unroll
        for (int j = 0; j < 4; ++j) {
            int off = wid * 1024 + j * 4096 + lane * 16;   // byte offset in 16KB tile
            int r = off >> 7, cb = off & 127;              // row, col-byte
            const char* gx = (const char*)xs  + (size_t)(m0 + r) * 1024 + ks * 128 + cb;
            const char* gz = (const char*)wzs + (size_t)(n0 + r) * 1024 + ks * 128 + cb;
            const char* gh = (const char*)whs + (size_t)(n0 + r) * 1024 + ks * 128 + cb;
            GLDS(gx, (char*)lx  + wid * 1024 + j * 4096);
            GLDS(gz, (char*)lwz + wid * 1024 + j * 4096);
            GLDS(gh, (char*)lwh + wid * 1024 + j * 4096);
        }
        __syncthreads();
#pragma unroll
        for (int kk = 0; kk < 2; ++kk) {
            bf16x8 af[4], bzf[4], bhf[4];
#pragma unroll
            for (int mf = 0; mf < 4; ++mf) {
                int r = wm * 64 + mf * 16 + lr;
                int q = (kk * 4 + lg) ^ (r & 7);
                af[mf] = *(const bf16x8*)((const char*)lx + r * 128 + q * 16);
            }
#pragma unroll
            for (int nf = 0; nf < 4; ++nf) {
                int r = wn * 64 + nf * 16 + lr;
                int q = (kk * 4 + lg) ^ (r & 7);
                bzf[nf] = *(const bf16x8*)((const char*)lwz + r * 128 + q * 16);
                bhf[nf] = *(const bf16x8*)((const char*)lwh + r * 128 + q * 16);
            }
#pragma unroll
            for (int mf = 0; mf < 4; ++mf)
#pragma unroll
                for (int nf = 0; nf < 4; ++nf) {
                    acck[mf][nf] = __builtin_amdgcn_mfma_f32_16x16x32_bf16(af[mf], bzf[nf], acck[mf][nf], 0, 0, 0);
                    accp[mf][nf] = __builtin_amdgcn_mfma_f32_16x16x32_bf16(af[mf], bhf[nf], accp[mf][nf], 0, 0, 0);
                }
        }
        __syncthreads();
    }

    // Epilogue. C/D layout: col=lane&15, row=(lane>>4)*4+j  [m89-verified].
    // This block covers chunks (blockIdx.x*2 + wm) of 64 timesteps each.
#pragma unroll
    for (int nf = 0; nf < 4; ++nf) {
        int h = n0 + wn * 64 + nf * 16 + lr;
        float bzv = bz[h], bhv = bh[h];
        float Acomb = 1.f, Bcomb = 0.f;   // composed over mf (time-ascending)
#pragma unroll
        for (int mf = 0; mf < 4; ++mf) {
            float As = 1.f, Bs = 0.f;     // this thread's 4-row segment
#pragma unroll
            for (int j = 0; j < 4; ++j) {
                int row = m0 + wm * 64 + mf * 16 + lg * 4 + j;
                float kv = acck[mf][nf][j] + bzv;
                float pv = accp[mf][nf][j] + bhv;
                float av = 1.0f / (1.0f + __expf(kv));           // 1-z = sigmoid(-k)
                float zv = 1.0f - av;
                float gv = (pv >= 0.0f) ? (pv + 0.5f) : (1.0f / (1.0f + __expf(-pv)));
                float bvv = zv * gv;
                __half2 hp = __floats2half2_rn(av, bvv);
                pk[(size_t)row * 512 + h] = *(unsigned int*)&hp;
                Bs = fmaf(av, Bs, bvv);
                As *= av;
            }
            // compose the 4 lane-group segments in time order (lg ascending)
            float Ag = 1.f, Bg = 0.f;
#pragma unroll
            for (int g = 0; g < 4; ++g) {
                float Ai = __shfl(As, lr + g * 16, 64);
                float Bi = __shfl(Bs, lr + g * 16, 64);
                Bg = fmaf(Ai, Bg, Bi);
                Ag *= Ai;
            }
            Bcomb = fmaf(Ag, Bcomb, Bg);
            Acomb *= Ag;
        }
        if (lg == 0) {
            int cg = blockIdx.x * 2 + wm;   // == b*NC + c
            agg[(size_t)cg * 512 + h] = make_float2(Acomb, Bcomb);
        }
    }
}

// Phase 2: sequential scan over chunk aggregates, emitting carry-in per chunk.
__global__ void scan_p2(const float* __restrict__ h0, const float2* __restrict__ agg,
                        float* __restrict__ carry) {
    int g = blockIdx.x * 256 + threadIdx.x;   // 0..2047
    int b = g >> 9, h = g & 511;
    float v = h0[b * 512 + h];
    float s = (v >= 0.f) ? (v + 0.5f) : (1.f / (1.f + __expf(-v)));   // g(h_0)
    for (int c = 0; c < NC; ++c) {
        size_t o = ((size_t)(b * NC + c)) * 512 + h;
        carry[o] = s;
        float2 ab = agg[o];
        s = fmaf(ab.x, s, ab.y);
    }
}

// Phase 3: replay recurrence within chunk from packed half2 (a,b), write h.
__global__ void scan_p3(const float* __restrict__ carry, const unsigned int* __restrict__ pk,
                        float* __restrict__ out) {
    int c = blockIdx.x, b = blockIdx.y;
    int h2 = threadIdx.x;                     // 2 columns per thread
    size_t co = ((size_t)(b * NC + c)) * 512 + h2 * 2;
    float2 s = *(const float2*)(carry + co);
    size_t base = ((size_t)(b * LL + c * CHUNK)) * 512 + h2 * 2;
    for (int t = 0; t < CHUNK; ++t) {
        uint2 u = *(const uint2*)(pk + base);
        float2 ab0 = __half22float2(*(__half2*)&u.x);
        float2 ab1 = __half22float2(*(__half2*)&u.y);
        s.x = fmaf(ab0.x, s.x, ab0.y);
        s.y = fmaf(ab1.x, s.y, ab1.y);
        *(float2*)(out + base) = s;
        base += 512;
    }
}

extern "C" void kernel_launch(void* const* d_in, const int* in_sizes, int n_in,
                              void* d_out, int out_size, void* d_ws, size_t ws_size,
                              hipStream_t stream) {
    const float* x  = (const float*)d_in[0];
    const float* h0 = (const float*)d_in[1];
    const float* Wz = (const float*)d_in[2];
    const float* bz = (const float*)d_in[3];
    const float* Wh = (const float*)d_in[4];
    const float* bh = (const float*)d_in[5];
    float* out = (float*)d_out;

    // workspace layout (~100 MB)
    unsigned short* xs  = (unsigned short*)d_ws;                 // 32 MB
    unsigned short* wzs = xs + (size_t)MM * 512;                 // 0.5 MB
    unsigned short* whs = wzs + (size_t)512 * 512;               // 0.5 MB
    unsigned int* pkbuf = (unsigned int*)(whs + (size_t)512 * 512);  // 64 MB
    float2* agg  = (float2*)(pkbuf + (size_t)MM * 512);          // 2 MB
    float* carry = (float*)(agg + (size_t)BB * NC * 512);        // 1 MB

    cvt_swz<<<8192, 256, 0, stream>>>(x, xs, MM);
    cvt_swz<<<128, 256, 0, stream>>>(Wz, wzs, 512);
    cvt_swz<<<128, 256, 0, stream>>>(Wh, whs, 512);
    gemm_gate<<<dim3(256, 4), 256, 0, stream>>>(xs, wzs, whs, bz, bh, pkbuf, agg);
    scan_p2<<<8, 256, 0, stream>>>(h0, agg, carry);
    scan_p3<<<dim3(NC, BB), 256, 0, stream>>>(carry, pkbuf, out);
}